// Round 4
// baseline (277.999 us; speedup 1.0000x reference)
//
#include <hip/hip_runtime.h>
#include <math.h>

#define NVOX 110592   // 48*48*48

typedef _Float16 f16x8 __attribute__((ext_vector_type(8)));
typedef _Float16 f16x4 __attribute__((ext_vector_type(4)));
typedef _Float16 f16x2 __attribute__((ext_vector_type(2)));
typedef float    f32x4 __attribute__((ext_vector_type(4)));

__device__ __forceinline__ float comp4(const float4& v, int j) {
    return j == 0 ? v.x : (j == 1 ? v.y : (j == 2 ? v.z : v.w));
}

// XCD-aware bijective swizzle (8 XCDs; grid % 8 == 0). Neighbor (d,h) rows
// share 2/3 of their halo -> keep them on the same XCD's L2.
__device__ __forceinline__ int xcd_swizzle(int bx, int nwg) {
    int chunk = nwg >> 3;
    return (bx & 7) * chunk + (bx >> 3);
}

// ---------------------------------------------------------------------------
// K0: merged prep.
//  blocks [0,1728):      feat [32 c][NVOX] f32 -> featT [NVOX][32 c] f16
//  blocks [1728,3456):   x    [32 c][NVOX] f32 -> xT32  [NVOX][32 c] f32
//  blocks [3456,3728):   weights
//   w1 [64][32][27] f32 -> w1h [64 oc][27 tap][32 ci] f16
//   w2 [216][64] f32    -> w2h [224 oc][64 ci] f16 (rows 216.. zero)
// ---------------------------------------------------------------------------
__global__ __launch_bounds__(256) void k_prep(
    const float* __restrict__ feat, const float* __restrict__ x,
    const float* __restrict__ w1, const float* __restrict__ w2,
    _Float16* __restrict__ featT, float* __restrict__ xT32,
    _Float16* __restrict__ w1h, _Float16* __restrict__ w2h)
{
    __shared__ float tileb[64 * 34];          // 8704 B; f16 path aliases
    int bx = blockIdx.x;
    int t = threadIdx.x;

    if (bx >= 3456) {                         // weight prep
        int e = (bx - 3456) * 256 + t;
        if (e < 64 * 32 * 27) {
            int oc = e / 864;
            int r = e - oc * 864;
            int ci = r / 27;
            int tap = r - ci * 27;
            w1h[oc * 864 + tap * 32 + ci] = (_Float16)w1[e];
        }
        int e2 = e - 55296;
        if (e2 >= 0 && e2 < 224 * 64) {
            int oc = e2 >> 6, k = e2 & 63;
            w2h[e2] = (oc < 216) ? (_Float16)w2[oc * 64 + k] : (_Float16)0.f;
        }
        return;
    }

    if (bx < 1728) {                          // feat -> f16 transpose
        _Float16* tile = (_Float16*)tileb;    // [64 dv][36 f16]
        int v0 = bx * 64;
        for (int i = t; i < 1024; i += 256) {
            int c2 = i >> 6, dv = i & 63;
            f16x2 v;
            v.x = (_Float16)feat[(2 * c2) * NVOX + v0 + dv];
            v.y = (_Float16)feat[(2 * c2 + 1) * NVOX + v0 + dv];
            *(f16x2*)(tile + dv * 36 + c2 * 2) = v;
        }
        __syncthreads();
        for (int i = t; i < 512; i += 256) {
            int dv = i >> 3, ch = i & 7;
            f16x4 v = *(const f16x4*)(tile + dv * 36 + ch * 4);
            *(f16x4*)(featT + (v0 + dv) * 32 + ch * 4) = v;
        }
        return;
    }

    // x -> f32 transpose (stride 34 f32: b64 accesses, 2-way max on write)
    {
        int v0 = (bx - 1728) * 64;
        for (int i = t; i < 1024; i += 256) {
            int c2 = i >> 6, dv = i & 63;
            float2 v;
            v.x = x[(2 * c2) * NVOX + v0 + dv];
            v.y = x[(2 * c2 + 1) * NVOX + v0 + dv];
            *(float2*)(tileb + dv * 34 + c2 * 2) = v;
        }
        __syncthreads();
        for (int i = t; i < 1024; i += 256) {
            int dv = i >> 4, ch = i & 15;
            float2 v = *(const float2*)(tileb + dv * 34 + ch * 2);
            *(float2*)(xT32 + (size_t)(v0 + dv) * 32 + ch * 2) = v;
        }
    }
}

// ---------------------------------------------------------------------------
// K1: fully fused per (d,h) row of 48 voxels, 512 threads (8 waves).
//  A: stage featT 3x3 halo -> X [450 col][40 f16]          (36 KB)
//  B: conv3x3x3 via MFMA, 6 waves x (px-block, oc-half): B-frag read ONCE
//  C: bias+SiLU -> hl [48 px][72 f16] (aliases X)
//  D: conv1x1 (64->216) via MFMA -> mbuf [8 sub][48 vox][28 f32] (43 KB)
//  E: softmax(27) in mbuf (384 thr)  — no x staging (x is L1/L2-resident)
//  F: 27-tap combine, 384 thr: 1 w-pos each, all 8 subs, 4 ch;
//     x read directly from global xT32 (f32: no cvt, no LDS)
// LDS 79,008 B -> 2 blocks/CU.
// ---------------------------------------------------------------------------
__global__ __launch_bounds__(512, 4) void k_main(
    const _Float16* __restrict__ featT, const float* __restrict__ xT32,
    const _Float16* __restrict__ w1h, const float* __restrict__ b1,
    const _Float16* __restrict__ w2h, const float* __restrict__ b2,
    float* __restrict__ out)
{
    __shared__ float smem[19752];              // 79,008 B
    float* mbuf = smem;                         // [8][48][28] f32
    _Float16* X  = (_Float16*)(smem + 10752);   // [450][40] f16 staging
    _Float16* hl = (_Float16*)(smem + 10752);   // [48][72] f16 (aliases X)

    int bx = xcd_swizzle(blockIdx.x, gridDim.x);
    int d = bx / 48, hh = bx - d * 48;
    int t = threadIdx.x;

    // ---- phase A: stage featT neighborhood (replicate-clamped)
    for (int i = t; i < 1800; i += 512) {
        int col = i >> 2, chunk = i & 3;        // col = dzdy*50 + px
        int dzdy = col / 50;
        int px = col - dzdy * 50;
        int dz = dzdy / 3, dy = dzdy - dz * 3;
        int zz = min(max(d + dz - 1, 0), 47);
        int yy = min(max(hh + dy - 1, 0), 47);
        int xx = min(max(px - 1, 0), 47);
        int vox = (zz * 48 + yy) * 48 + xx;
        *(f16x8*)(X + col * 40 + chunk * 8) =
            *(const f16x8*)(featT + vox * 32 + chunk * 8);
    }
    __syncthreads();

    int wid = t >> 6;                           // 0..7
    int lane = t & 63;
    int mcol = lane & 15;
    int q = lane >> 4;

    // ---- phase B: conv1 MFMA. 6 waves: wave = (px-block 0..2) x (oc-half)
    f32x4 c1a = {0.f, 0.f, 0.f, 0.f};
    f32x4 c1b = {0.f, 0.f, 0.f, 0.f};
    int pxb = wid >> 1;                         // 0..2 (waves 6,7 unused)
    int och = wid & 1;
    if (wid < 6) {
        const _Float16* wb0 = w1h + (och * 32 + mcol) * 864 + q * 8;
        const _Float16* wb1 = wb0 + 16 * 864;
#pragma unroll 3
        for (int dzdy = 0; dzdy < 9; ++dzdy) {
            const _Float16* brow = X + (dzdy * 50 + pxb * 16 + mcol) * 40 + q * 8;
            const _Float16* wr0 = wb0 + dzdy * 96;
            const _Float16* wr1 = wb1 + dzdy * 96;
#pragma unroll
            for (int dx = 0; dx < 3; ++dx) {
                f16x8 bv = *(const f16x8*)(brow + dx * 40);
                f16x8 a0 = *(const f16x8*)(wr0 + dx * 32);
                f16x8 a1 = *(const f16x8*)(wr1 + dx * 32);
                c1a = __builtin_amdgcn_mfma_f32_16x16x32_f16(a0, bv, c1a, 0, 0, 0);
                c1b = __builtin_amdgcn_mfma_f32_16x16x32_f16(a1, bv, c1b, 0, 0, 0);
            }
        }
    }
    __syncthreads();                            // all X reads done

    // ---- phase C: bias + SiLU -> hl (aliases X head)
    if (wid < 6) {
        int pxv = pxb * 16 + mcol;              // D: col = lane&15
        float4 bva = ((const float4*)b1)[(och * 2) * 4 + q];
        float4 bvb = ((const float4*)b1)[(och * 2 + 1) * 4 + q];
        f16x4 o; float s;
        s = c1a[0] + bva.x; o.x = (_Float16)(s / (1.f + __expf(-s)));
        s = c1a[1] + bva.y; o.y = (_Float16)(s / (1.f + __expf(-s)));
        s = c1a[2] + bva.z; o.z = (_Float16)(s / (1.f + __expf(-s)));
        s = c1a[3] + bva.w; o.w = (_Float16)(s / (1.f + __expf(-s)));
        *(f16x4*)(hl + pxv * 72 + och * 32 + q * 4) = o;
        s = c1b[0] + bvb.x; o.x = (_Float16)(s / (1.f + __expf(-s)));
        s = c1b[1] + bvb.y; o.y = (_Float16)(s / (1.f + __expf(-s)));
        s = c1b[2] + bvb.z; o.z = (_Float16)(s / (1.f + __expf(-s)));
        s = c1b[3] + bvb.w; o.w = (_Float16)(s / (1.f + __expf(-s)));
        *(f16x4*)(hl + pxv * 72 + och * 32 + 16 + q * 4) = o;
    }
    __syncthreads();                            // hl complete

    // ---- phase D: conv2 MFMA, 42 tiles (14 mt x 3 nt) over 8 waves
    for (int tt = wid; tt < 42; tt += 8) {
        int mt = tt / 3, nt = tt - mt * 3;
        float bias[4];
#pragma unroll
        for (int rr = 0; rr < 4; ++rr) {
            int oc = mt * 16 + q * 4 + rr;
            bias[rr] = (oc < 216) ? b2[oc] : 0.f;
        }
        f32x4 acc = {bias[0], bias[1], bias[2], bias[3]};
#pragma unroll
        for (int ks = 0; ks < 2; ++ks) {
            f16x8 av = *(const f16x8*)(w2h + (mt * 16 + mcol) * 64 + ks * 32 + q * 8);
            f16x8 bv = *(const f16x8*)(hl + (nt * 16 + mcol) * 72 + ks * 32 + q * 8);
            acc = __builtin_amdgcn_mfma_f32_16x16x32_f16(av, bv, acc, 0, 0, 0);
        }
        int vox = nt * 16 + mcol;
#pragma unroll
        for (int rr = 0; rr < 4; ++rr) {
            int oc = mt * 16 + q * 4 + rr;
            if (oc < 216) {
                int sub = oc / 27;
                int n = oc - sub * 27;
                mbuf[(sub * 48 + vox) * 28 + n] = acc[rr];
            }
        }
    }
    __syncthreads();                            // mbuf complete

    // ---- phase E: softmax over 27 taps (8 sub x 48 vox rows)
    if (t < 384) {
        int sub = t / 48;
        int vox = t - sub * 48;
        float4* p4p = (float4*)(mbuf + (sub * 48 + vox) * 28);
        float4 v[7];
#pragma unroll
        for (int g = 0; g < 7; ++g) v[g] = p4p[g];
        float mx = fmaxf(fmaxf(v[6].x, v[6].y), v[6].z);
#pragma unroll
        for (int g = 0; g < 6; ++g)
            mx = fmaxf(mx, fmaxf(fmaxf(v[g].x, v[g].y), fmaxf(v[g].z, v[g].w)));
        float s = 0.f;
#pragma unroll
        for (int g = 0; g < 7; ++g) {
            v[g].x = __expf(v[g].x - mx);
            v[g].y = __expf(v[g].y - mx);
            v[g].z = __expf(v[g].z - mx);
            v[g].w = __expf(v[g].w - mx);
        }
        v[6].w = 0.f;                           // tap 27 pad
#pragma unroll
        for (int g = 0; g < 7; ++g) s += v[g].x + v[g].y + v[g].z + v[g].w;
        float inv = 1.f / s;
#pragma unroll
        for (int g = 0; g < 7; ++g) {
            v[g].x *= inv; v[g].y *= inv; v[g].z *= inv; v[g].w *= inv;
            p4p[g] = v[g];
        }
    }
    __syncthreads();

    // ---- phase F: 384 thr: thread = (cq 8) x (tx 8) x (half 2) x (wig 3)
    // out[c][2d+i][2h+j][2w+k] = sum_n p[i*4+j*2+k][w][n] * x[c][nb(w,n)]
    if (t < 384) {
        int cq = t & 7;
        int tx = (t >> 3) & 7;
        int half = (t >> 6) & 1;
        int wig = t >> 7;                       // 0..2
        int w = half * 24 + wig * 8 + tx;

        int rb[9];
#pragma unroll
        for (int r = 0; r < 9; ++r) {
            int dz = r / 3, dy = r - (r / 3) * 3;
            int zz = min(max(d + dz - 1, 0), 47);
            int yy = min(max(hh + dy - 1, 0), 47);
            rb[r] = (zz * 48 + yy) * 48;
        }
        int xs0 = max(w - 1, 0), xs2 = min(w + 1, 47);

        float acc[8][4];
#pragma unroll
        for (int sub = 0; sub < 8; ++sub)
#pragma unroll
            for (int cc = 0; cc < 4; ++cc) acc[sub][cc] = 0.f;

        const float4* smem4 = (const float4*)smem;
#pragma unroll
        for (int g = 0; g < 7; ++g) {
            float4 p[8];
#pragma unroll
            for (int sub = 0; sub < 8; ++sub)
                p[sub] = smem4[(sub * 48 + w) * 7 + g];
#pragma unroll
            for (int j = 0; j < 4; ++j) {
                int n = g * 4 + j;
                if (n < 27) {
                    int r = n / 3;              // dz*3+dy (compile-time)
                    int dx = n - r * 3;
                    int xx = (dx == 0) ? xs0 : ((dx == 1) ? w : xs2);
                    float4 xv = *(const float4*)(xT32 +
                                  (size_t)(rb[r] + xx) * 32 + cq * 4);
#pragma unroll
                    for (int sub = 0; sub < 8; ++sub) {
                        float pv = comp4(p[sub], j);
                        acc[sub][0] = fmaf(xv.x, pv, acc[sub][0]);
                        acc[sub][1] = fmaf(xv.y, pv, acc[sub][1]);
                        acc[sub][2] = fmaf(xv.z, pv, acc[sub][2]);
                        acc[sub][3] = fmaf(xv.w, pv, acc[sub][3]);
                    }
                }
            }
        }

#pragma unroll
        for (int ij = 0; ij < 4; ++ij) {
            int i_ = ij >> 1, j_ = ij & 1;
            int rowz = 2 * d + i_;
            int rowy = 2 * hh + j_;
            int s0 = ij * 2;                    // sub for k=0
#pragma unroll
            for (int cc = 0; cc < 4; ++cc) {
                int c = cq * 4 + cc;
                float2 v;
                v.x = acc[s0][cc];              // k = 0
                v.y = acc[s0 + 1][cc];          // k = 1
                *(float2*)(out + (((size_t)c * 96 + rowz) * 96 + rowy) * 96 + 2 * w) = v;
            }
        }
    }
}

extern "C" void kernel_launch(void* const* d_in, const int* in_sizes, int n_in,
                              void* d_out, int out_size, void* d_ws, size_t ws_size,
                              hipStream_t stream) {
    const float* x    = (const float*)d_in[0];
    const float* feat = (const float*)d_in[1];
    const float* w1   = (const float*)d_in[2];
    const float* b1   = (const float*)d_in[3];
    const float* w2   = (const float*)d_in[4];
    const float* b2   = (const float*)d_in[5];
    float* out = (float*)d_out;

    _Float16* w1h   = (_Float16*)d_ws;                       //    110,592 B
    _Float16* w2h   = (_Float16*)((char*)d_ws + 110592);     //     28,672 B
    _Float16* featT = (_Float16*)((char*)d_ws + 139264);     //  7,077,888 B
    float*    xT32  = (float*)((char*)d_ws + 7217152);       // 14,155,776 B

    k_prep<<<3728, 256, 0, stream>>>(feat, x, w1, w2, featT, xT32, w1h, w2h);
    k_main<<<2304, 512, 0, stream>>>(featT, xT32, w1h, b1, w2h, b2, out);
}